// Round 2
// baseline (202.070 us; speedup 1.0000x reference)
//
#include <hip/hip_runtime.h>
#include <hip/hip_bf16.h>

// x: (32, 512) int32 in [0,16); pos_enc: (5000, 384) f32;
// out: (32, T, 384) f32, T = out_size / (32*384).
//
// Structural identity: for token (b,j) with count c = x[b,j], the output rows
// starts[b,j] .. starts[b,j]+c-1 are exactly pe[0..c-1] -- a contiguous copy
// of the first c*384 floats of pos_enc. So the writer is a pure segment
// memcpy from an L1-resident <=23KB source. No searchsorted, no gather.

#define B 32
#define L 512
#define D 384
#define D4 (D / 4)   // 96 float4 per row

// ---------------------------------------------------------------------------
// Kernel 1: per-row inclusive cumsum of x (32 rows x 512). One wave per row.
// ---------------------------------------------------------------------------
__global__ __launch_bounds__(64) void pe_cumsum_kernel(
    const int* __restrict__ x, int* __restrict__ cs) {
  const int b = blockIdx.x;
  const int lane = threadIdx.x;  // 0..63
  const int base = b * L + lane * 8;

  const int4* xr = reinterpret_cast<const int4*>(x + base);
  int4 a = xr[0];
  int4 c = xr[1];
  int v[8] = {a.x, a.y, a.z, a.w, c.x, c.y, c.z, c.w};

  int pref[8];
  int s = 0;
#pragma unroll
  for (int k = 0; k < 8; ++k) { s += v[k]; pref[k] = s; }

  int acc = s;
#pragma unroll
  for (int off = 1; off < 64; off <<= 1) {
    int n = __shfl_up(acc, off);
    if (lane >= off) acc += n;
  }
  const int offset = acc - s;

  int4 o0 = make_int4(offset + pref[0], offset + pref[1],
                      offset + pref[2], offset + pref[3]);
  int4 o1 = make_int4(offset + pref[4], offset + pref[5],
                      offset + pref[6], offset + pref[7]);
  int4* cr = reinterpret_cast<int4*>(cs + base);
  cr[0] = o0;
  cr[1] = o1;
}

// ---------------------------------------------------------------------------
// Kernel 2: segment copy. Block (j, b) copies pe[0 : c*384] to
// out[b, starts[b,j], :]. c <= 15 -> n <= 1440 float4 (23KB, L1-resident
// source). Stores are contiguous float4 -> full-cacheline streaming writes.
// ---------------------------------------------------------------------------
__global__ __launch_bounds__(256) void pe_segcopy_kernel(
    const int* __restrict__ x, const int* __restrict__ cs,
    const float4* __restrict__ pe, float4* __restrict__ out, int T) {
  const int j = blockIdx.x;
  const int b = blockIdx.y;
  const int c = x[b * L + j];
  if (c == 0) return;
  const int start = cs[b * L + j] - c;

  float4* dst = out + ((size_t)b * T + start) * D4;
  const int n = c * D4;  // <= 1440
  for (int i = threadIdx.x; i < n; i += 256) {
    dst[i] = pe[i];
  }
}

// ---------------------------------------------------------------------------
// Kernel 3: zero-fill the tail rows t in [total[b], T).
// ---------------------------------------------------------------------------
__global__ __launch_bounds__(256) void pe_tailzero_kernel(
    const int* __restrict__ cs, float4* __restrict__ out, int T) {
  const int b = blockIdx.y;
  const int total = cs[b * L + (L - 1)];
  const int n = (T - total) * D4;
  float4* dst = out + ((size_t)b * T + total) * D4;
  const float4 z = make_float4(0.f, 0.f, 0.f, 0.f);
  const int stride = gridDim.x * 256;
  for (int i = blockIdx.x * 256 + threadIdx.x; i < n; i += stride) {
    dst[i] = z;
  }
}

// ---------------------------------------------------------------------------
extern "C" void kernel_launch(void* const* d_in, const int* in_sizes, int n_in,
                              void* d_out, int out_size, void* d_ws, size_t ws_size,
                              hipStream_t stream) {
  const int* x = (const int*)d_in[0];       // (32, 512) int32
  const float* pe = (const float*)d_in[1];  // (5000, 384) f32
  float* out = (float*)d_out;               // (32, T, 384) f32

  const int T = out_size / (B * D);

  int* cs = (int*)d_ws;  // 32*512 ints

  pe_cumsum_kernel<<<B, 64, 0, stream>>>(x, cs);

  dim3 g2(L, B);
  pe_segcopy_kernel<<<g2, 256, 0, stream>>>(x, cs, (const float4*)pe,
                                            (float4*)out, T);

  dim3 g3(32, B);
  pe_tailzero_kernel<<<g3, 256, 0, stream>>>(cs, (float4*)out, T);
}